// Round 1
// baseline (70471.387 us; speedup 1.0000x reference)
//
#include <hip/hip_runtime.h>
#include <math.h>

// ---------------- model dims ----------------
constexpr int Dc = 768;
constexpr int HEADS = 8, DHh = 96;
constexpr long TOK = 32768;           // B*N*T = 4*128*64
constexpr long HALF = TOK * Dc;       // 25165824 elements (y half / h half)
// mamba
constexpr int LD_ZX = 3224;           // in_proj out width
constexpr int LD_XC = 1664;           // conv dim
// flags
constexpr int FLAG_ACC = 1, FLAG_GELU = 2, FLAG_PERM = 4;

// ---------------- GEMM: C = [beta*C +] act(A@B + bias) ----------------
// A: MxK row-major (lda), B: KxN row-major (ldb), C: MxN (ldc).
// M % 64 == 0, K % 16 == 0 required. N arbitrary (guarded).
__global__ __launch_bounds__(256) void gemm_kernel(
    const float* __restrict__ A, int lda,
    const float* __restrict__ B, int ldb,
    const float* __restrict__ bias,
    float* __restrict__ C, int ldc,
    int M, int N, int K, int flags)
{
    __shared__ float As[16][65];
    __shared__ float Bs[16][65];
    const int bm = blockIdx.y * 64;
    const int bn = blockIdx.x * 64;
    const int tid = threadIdx.x;
    const int tx = tid & 15, ty = tid >> 4;
    float acc[4][4] = {};
    for (int k0 = 0; k0 < K; k0 += 16) {
#pragma unroll
        for (int i = 0; i < 4; i++) {
            int lin = tid + i * 256;        // 64x16 A tile
            int m = lin >> 4, k = lin & 15;
            As[k][m] = A[(long)(bm + m) * lda + k0 + k];
        }
#pragma unroll
        for (int i = 0; i < 4; i++) {
            int lin = tid + i * 256;        // 16x64 B tile
            int k = lin >> 6, n = lin & 63;
            Bs[k][n] = (bn + n < N) ? B[(long)(k0 + k) * ldb + bn + n] : 0.f;
        }
        __syncthreads();
#pragma unroll
        for (int k = 0; k < 16; k++) {
            float a[4], b[4];
#pragma unroll
            for (int i = 0; i < 4; i++) a[i] = As[k][ty * 4 + i];
#pragma unroll
            for (int j = 0; j < 4; j++) b[j] = Bs[k][tx * 4 + j];
#pragma unroll
            for (int i = 0; i < 4; i++)
#pragma unroll
                for (int j = 0; j < 4; j++) acc[i][j] += a[i] * b[j];
        }
        __syncthreads();
    }
#pragma unroll
    for (int i = 0; i < 4; i++) {
        int m = bm + ty * 4 + i;
#pragma unroll
        for (int j = 0; j < 4; j++) {
            int n = bn + tx * 4 + j;
            if (n >= N) continue;
            float v = acc[i][j];
            if (bias) v += bias[n];
            if (flags & FLAG_GELU) {
                float x = v;
                float t = tanhf(0.7978845608028654f * (x + 0.044715f * x * x * x));
                v = 0.5f * x * (1.0f + t);
            }
            long oidx;
            if (flags & FLAG_PERM) {
                // m is z-row (b*64+t)*128+n_ -> out row (b*128+n_)*64+t
                int b_ = m >> 13, t_ = (m >> 7) & 63, n_ = m & 127;
                long orow = ((long)(b_ * 128 + n_)) * 64 + t_;
                oidx = orow * (long)ldc + n;
            } else {
                oidx = (long)m * ldc + n;
            }
            if (flags & FLAG_ACC) C[oidx] += v;
            else C[oidx] = v;
        }
    }
}

// ---------------- RMSNorm (optionally strided / in-place) ----------------
__global__ void rmsnorm_kernel(const float* __restrict__ x, const float* __restrict__ w,
                               float* __restrict__ out, int D, int xstride, int ostride)
{
    const long row = blockIdx.x;
    const float* xr = x + row * (long)xstride;
    float* orow = out + row * (long)ostride;
    float ss = 0.f;
    for (int i = threadIdx.x; i < D; i += 256) { float v = xr[i]; ss += v * v; }
    __shared__ float red[256];
    red[threadIdx.x] = ss;
    __syncthreads();
    for (int s = 128; s > 0; s >>= 1) {
        if (threadIdx.x < s) red[threadIdx.x] += red[threadIdx.x + s];
        __syncthreads();
    }
    float scale = rsqrtf(red[0] / D + 1e-5f);
    for (int i = threadIdx.x; i < D; i += 256) orow[i] = xr[i] * scale * w[i];
}

// ---------------- fused attention: per (batch, head), 64x64 scores ----------------
__global__ __launch_bounds__(256) void attn_kernel(
    const float* __restrict__ Q, const float* __restrict__ K,
    const float* __restrict__ V, float* __restrict__ O)
{
    __shared__ float Qs[64 * 96];   // later reused for V
    __shared__ float Ks[64 * 96];   // first 4096 reused for P
    const int b = blockIdx.x >> 3, h = blockIdx.x & 7;
    const int tid = threadIdx.x;
    const long base = (long)b * 64 * 768 + h * 96;
    for (int i = tid; i < 6144; i += 256) {
        int t = i / 96, d = i - t * 96;
        Qs[i] = Q[base + (long)t * 768 + d];
        Ks[i] = K[base + (long)t * 768 + d];
    }
    __syncthreads();
    const int i_ = tid >> 2, j0 = (tid & 3) << 4;
    float sv[16];
    const float scale = 0.102062072615966f;   // 1/sqrt(96)
#pragma unroll
    for (int jj = 0; jj < 16; jj++) {
        float s = 0.f;
        const float* qr = &Qs[i_ * 96];
        const float* kr = &Ks[(j0 + jj) * 96];
        for (int d = 0; d < 96; d++) s += qr[d] * kr[d];
        sv[jj] = s * scale;
    }
    // quad-wise softmax over the 64-wide row (4 threads per row)
    float mx = sv[0];
#pragma unroll
    for (int jj = 1; jj < 16; jj++) mx = fmaxf(mx, sv[jj]);
    mx = fmaxf(mx, __shfl_xor(mx, 1));
    mx = fmaxf(mx, __shfl_xor(mx, 2));
    float sum = 0.f;
#pragma unroll
    for (int jj = 0; jj < 16; jj++) { sv[jj] = expf(sv[jj] - mx); sum += sv[jj]; }
    sum += __shfl_xor(sum, 1);
    sum += __shfl_xor(sum, 2);
    float inv = 1.f / sum;
    __syncthreads();               // done reading Qs/Ks for scores
    float* Ps = Ks;                // reuse K tile for probabilities
#pragma unroll
    for (int jj = 0; jj < 16; jj++) Ps[i_ * 64 + j0 + jj] = sv[jj] * inv;
    for (int i = tid; i < 6144; i += 256) { // V into Qs
        int t = i / 96, d = i - t * 96;
        Qs[i] = V[base + (long)t * 768 + d];
    }
    __syncthreads();
    for (int i = tid; i < 6144; i += 256) {
        int t = i / 96, d = i - t * 96;
        float o = 0.f;
        for (int k = 0; k < 64; k++) o += Ps[t * 64 + k] * Qs[k * 96 + d];
        O[base + (long)t * 768 + d] = o;
    }
}

// ---------------- transpose p (B,N,T,D) -> z (B,T,N,D) rows ----------------
__global__ void transpose_kernel(const float* __restrict__ P, float* __restrict__ Z)
{
    long lin = (long)blockIdx.x * 256 + threadIdx.x;
    if (lin >= HALF) return;
    int d = (int)(lin % 768);
    long rowz = lin / 768;
    int n = rowz & 127, t = (int)((rowz >> 7) & 63), b = (int)(rowz >> 13);
    long rowp = ((long)(b * 128 + n)) * 64 + t;
    Z[lin] = P[rowp * 768 + d];
}

// ---------------- causal depthwise conv (window 4) + SiLU ----------------
__global__ void conv_kernel(const float* __restrict__ zx, const float* __restrict__ cw,
                            const float* __restrict__ cb, float* __restrict__ xc, int rows)
{
    long lin = (long)blockIdx.x * 256 + threadIdx.x;
    if (lin >= (long)rows * LD_XC) return;
    int c = (int)(lin % LD_XC);
    int r = (int)(lin / LD_XC);
    int n = r & 127;
    float acc = cb[c];
#pragma unroll
    for (int k = 0; k < 4; k++) {
        int nn = n - 3 + k;
        if (nn >= 0) acc += cw[k * LD_XC + c] * zx[(long)(r - 3 + k) * LD_ZX + 1536 + c];
    }
    acc = acc / (1.f + expf(-acc));   // silu
    xc[(long)r * LD_XC + c] = acc;
}

// ---------------- dt = softplus(dt_raw + bias), in place ----------------
__global__ void dt_kernel(float* __restrict__ zx, const float* __restrict__ bias, long count)
{
    long lin = (long)blockIdx.x * 256 + threadIdx.x;
    if (lin >= count) return;
    int h = (int)(lin % 24);
    long r = lin / 24;
    float v = zx[r * LD_ZX + 3200 + h] + bias[h];
    float sp = (v > 0.f) ? v + log1pf(expf(-v)) : log1pf(expf(v));
    zx[r * LD_ZX + 3200 + h] = sp;
}

// ---------------- SSM scan: 1 wave per (batch, head), state in registers ----------------
__global__ __launch_bounds__(64) void scan_kernel(
    const float* __restrict__ zx,   // chunk base, ld 3224 (z gate + dt)
    float* __restrict__ xc,         // chunk base, ld 1664 (xs,B,C in; gated y out)
    const float* __restrict__ Alog, const float* __restrict__ Dskip,
    float* __restrict__ hout, int bt0)
{
    const int btl = blockIdx.x / 24, h = blockIdx.x % 24;
    const int lane = threadIdx.x;   // p index
    const float A = -expf(Alog[h]);
    const float Dh = Dskip[h];
    float hs[64];
#pragma unroll
    for (int s = 0; s < 64; s++) hs[s] = 0.f;
    __shared__ float Bsh[64], Csh[64];
    const long rbase = (long)btl * 128;
    for (int t = 0; t < 128; t++) {
        const long r = rbase + t;
        float x = xc[r * LD_XC + h * 64 + lane];
        Bsh[lane] = xc[r * LD_XC + 1536 + lane];
        Csh[lane] = xc[r * LD_XC + 1600 + lane];
        float dt = zx[r * LD_ZX + 3200 + h];
        __syncthreads();
        float dA = expf(dt * A);
        float coef = dt * x;
        float acc = 0.f;
#pragma unroll
        for (int s = 0; s < 64; s++) {
            hs[s] = hs[s] * dA + coef * Bsh[s];
            acc += hs[s] * Csh[s];
        }
        float zg = zx[r * LD_ZX + h * 64 + lane];
        float y = (acc + Dh * x) * (zg / (1.f + expf(-zg)));
        xc[r * LD_XC + h * 64 + lane] = y;   // in-place gated output
        __syncthreads();                     // protect Bsh/Csh before next stage
    }
    if (hout) {
        long base = ((long)(bt0 + btl) * 24 + h) * 4096 + (long)lane * 64;
#pragma unroll
        for (int s = 0; s < 64; s++) hout[base + s] = hs[s];
    }
}

// ---------------- host orchestration ----------------
extern "C" void kernel_launch(void* const* d_in, const int* in_sizes, int n_in,
                              void* d_out, int out_size, void* d_ws, size_t ws_size,
                              hipStream_t stream)
{
    const float* precepts  = (const float*)d_in[0];
    const float* actions   = (const float*)d_in[1];
    const float* attn_n1   = (const float*)d_in[2];
    const float* Wq        = (const float*)d_in[3];
    const float* Wk        = (const float*)d_in[4];
    const float* Wv        = (const float*)d_in[5];
    const float* Wo        = (const float*)d_in[6];
    const float* attn_n2   = (const float*)d_in[7];
    const float* ffn_w1    = (const float*)d_in[8];
    const float* ffn_b1    = (const float*)d_in[9];
    const float* ffn_w2    = (const float*)d_in[10];
    const float* ffn_b2    = (const float*)d_in[11];
    const float* ssm_norm  = (const float*)d_in[12];
    const float* in_proj   = (const float*)d_in[13];
    const float* conv_w    = (const float*)d_in[14];
    const float* conv_b    = (const float*)d_in[15];
    const float* dt_bias   = (const float*)d_in[16];
    const float* A_log     = (const float*)d_in[17];
    const float* D_skip    = (const float*)d_in[18];
    const float* mamba_nw  = (const float*)d_in[19];
    const float* out_proj  = (const float*)d_in[20];
    const float* proj_w    = (const float*)d_in[21];
    const float* proj_b    = (const float*)d_in[22];

    float* out  = (float*)d_out;
    float* P    = out + HALF;     // residual stream lives in d_out[HALF..), dead before h_last write
    float* hout = out + HALF;
    float* ws   = (float*)d_ws;

    const size_t wsf = ws_size / sizeof(float);
    int CBT = 64;   // mamba batch chunk
    while (CBT > 2 && (25165824ull + (unsigned long long)CBT * 723968ull) > wsf) CBT >>= 1;
    int CB = 128;   // attention batch chunk
    while (CB > 16 && 4ull * (unsigned long long)CB * 49152ull > wsf) CB >>= 1;

    auto gemm = [&](const float* A, int lda, const float* B, int ldb, const float* bias,
                    float* C, int ldc, int M, int N, int K, int flags) {
        dim3 g((N + 63) / 64, M / 64);
        hipLaunchKernelGGL(gemm_kernel, g, dim3(256), 0, stream,
                           A, lda, B, ldb, bias, C, ldc, M, N, K, flags);
    };

    // ---------- attention stack ----------
    hipMemcpyAsync(P, precepts, HALF * sizeof(float), hipMemcpyDeviceToDevice, stream);
    float* bufA = ws;
    float* bufQ = bufA + (long)CB * 49152;
    float* bufK = bufQ + (long)CB * 49152;
    float* bufV = bufK + (long)CB * 49152;
    const int nac = 512 / CB;
    for (int layer = 0; layer < 4; layer++) {
        const bool cross = ((layer + 1) % 2) == 0;
        for (int c = 0; c < nac; c++) {
            const long tok0 = (long)c * CB * 64;
            const int Mr = CB * 64;
            float* Pc = P + tok0 * 768;
            hipLaunchKernelGGL(rmsnorm_kernel, dim3(Mr), dim3(256), 0, stream,
                               Pc, attn_n1 + layer * 768, bufA, 768, 768, 768);
            gemm(bufA, 768, Wq + (long)layer * 589824, 768, nullptr, bufQ, 768, Mr, 768, 768, 0);
            const float* kvsrc = cross ? actions + tok0 * 768 : bufA;
            gemm(kvsrc, 768, Wk + (long)layer * 589824, 768, nullptr, bufK, 768, Mr, 768, 768, 0);
            gemm(kvsrc, 768, Wv + (long)layer * 589824, 768, nullptr, bufV, 768, Mr, 768, 768, 0);
            hipLaunchKernelGGL(attn_kernel, dim3(CB * 8), dim3(256), 0, stream,
                               bufQ, bufK, bufV, bufA);
            gemm(bufA, 768, Wo + (long)layer * 589824, 768, nullptr, Pc, 768, Mr, 768, 768, FLAG_ACC);
            hipLaunchKernelGGL(rmsnorm_kernel, dim3(Mr), dim3(256), 0, stream,
                               Pc, attn_n2 + layer * 768, bufA, 768, 768, 768);
            for (int hc = 0; hc < 4; hc++) {   // FFN hidden chunked 3072 -> 4x768
                gemm(bufA, 768, ffn_w1 + (long)layer * 768 * 3072 + hc * 768, 3072,
                     ffn_b1 + layer * 3072 + hc * 768, bufQ, 768, Mr, 768, 768, FLAG_GELU);
                gemm(bufQ, 768, ffn_w2 + (long)layer * 3072 * 768 + (long)hc * 768 * 768, 768,
                     hc == 0 ? ffn_b2 + layer * 768 : nullptr, Pc, 768, Mr, 768, 768, FLAG_ACC);
            }
        }
    }

    // ---------- transpose to SSM layout ----------
    float* Z = ws;   // attention scratch is dead now
    hipLaunchKernelGGL(transpose_kernel, dim3((HALF + 255) / 256), dim3(256), 0, stream, P, Z);

    // ---------- mamba blocks ----------
    float* xn = ws + 25165824;
    float* zx = xn + (long)CBT * 98304;
    float* xc = zx + (long)CBT * 412672;
    const int nmc = 256 / CBT;
    for (int m = 0; m < 4; m++) {
        for (int c = 0; c < nmc; c++) {
            const long row0 = (long)c * CBT * 128;
            const int Mr = CBT * 128;
            float* Zc = Z + row0 * 768;
            hipLaunchKernelGGL(rmsnorm_kernel, dim3(Mr), dim3(256), 0, stream,
                               Zc, ssm_norm + m * 768, xn, 768, 768, 768);
            gemm(xn, 768, in_proj + (long)m * 768 * 3224, 3224, nullptr,
                 zx, 3224, Mr, 3224, 768, 0);
            const long convn = (long)Mr * LD_XC;
            hipLaunchKernelGGL(conv_kernel, dim3((convn + 255) / 256), dim3(256), 0, stream,
                               zx, conv_w + m * 4 * 1664, conv_b + m * 1664, xc, Mr);
            const long dtn = (long)Mr * 24;
            hipLaunchKernelGGL(dt_kernel, dim3((dtn + 255) / 256), dim3(256), 0, stream,
                               zx, dt_bias + m * 24, dtn);
            hipLaunchKernelGGL(scan_kernel, dim3(CBT * 24), dim3(64), 0, stream,
                               zx, xc, A_log + m * 24, D_skip + m * 24,
                               (m == 3) ? hout : nullptr, c * CBT);
            hipLaunchKernelGGL(rmsnorm_kernel, dim3(Mr), dim3(256), 0, stream,
                               xc, mamba_nw + m * 1536, xc, 1536, 1664, 1664);
            gemm(xc, 1664, out_proj + (long)m * 1536 * 768, 768, nullptr,
                 Zc, 768, Mr, 768, 1536, FLAG_ACC);
        }
    }

    // ---------- final projection with permuted epilogue ----------
    gemm(Z, 768, proj_w, 768, proj_b, out, 768, 32768, 768, 768, FLAG_PERM);
}

// Round 2
// 15496.400 us; speedup vs baseline: 4.5476x; 4.5476x over previous
//
#include <hip/hip_runtime.h>
#include <hip/hip_bf16.h>
#include <math.h>

// ---------------- model dims ----------------
constexpr long TOK  = 32768;            // B*N*T = 4*128*64
constexpr long HALF = TOK * 768;        // elements of each output half
constexpr int LD_ZX = 3224;             // in_proj out width
constexpr int LD_XC = 1664;             // conv dim
// epilogue flags
constexpr int FLAG_ACC = 1, FLAG_GELU = 2, FLAG_PERM = 4, FLAG_BF16 = 8;

typedef __bf16 bf16x8 __attribute__((ext_vector_type(8)));
typedef float  f32x4  __attribute__((ext_vector_type(4)));

__device__ __forceinline__ void gload_lds16(const void* g, void* l) {
    __builtin_amdgcn_global_load_lds(
        (const __attribute__((address_space(1))) void*)g,
        (__attribute__((address_space(3))) void*)l, 16, 0, 0);
}

// ---------------- bf16 MFMA GEMM ----------------
// A: MxK bf16 row-major (dense, lda=K). BT: Npad x K bf16 row-major (B transposed).
// C: f32 (or bf16 with FLAG_BF16), ldc. grid = (Npad/128, M/128), 256 threads.
__global__ __launch_bounds__(256) void gemm_bf16(
    const __hip_bfloat16* __restrict__ A,
    const __hip_bfloat16* __restrict__ BT,
    const float* __restrict__ bias,
    void* __restrict__ Cv, int ldc,
    int M, int N, int K, int flags, int moff)
{
    __shared__ __hip_bfloat16 As[128 * 32];
    __shared__ __hip_bfloat16 Bs[128 * 32];
    const int tid = threadIdx.x;
    const int wv = tid >> 6, lane = tid & 63;
    const int bm = blockIdx.y * 128, bn = blockIdx.x * 128;
    const int wr = (wv >> 1) * 64, wc = (wv & 1) * 64;
    const int lrow = lane & 15, lk = lane >> 4;
    const int ck = (lk ^ (lrow & 3)) * 8;   // swizzled k-chunk for frag reads

    f32x4 acc[4][4];
#pragma unroll
    for (int m = 0; m < 4; m++)
#pragma unroll
        for (int n = 0; n < 4; n++) acc[m][n] = f32x4{0.f, 0.f, 0.f, 0.f};

    for (int k0 = 0; k0 < K; k0 += 32) {
#pragma unroll
        for (int i = 0; i < 2; i++) {
            const int lin = i * 256 + tid;          // 0..511
            const int row = lin >> 2;
            const int ks  = (((lin & 3) ^ (row & 3)) * 8);  // swizzled source chunk
            const long asrc = (long)(bm + row) * K + k0 + ks;
            const long bsrc = (long)(bn + row) * K + k0 + ks;
            char* la = (char*)As + (i * 256 + wv * 64) * 16; // wave-uniform base
            char* lb = (char*)Bs + (i * 256 + wv * 64) * 16;
            gload_lds16(A + asrc, la);
            gload_lds16(BT + bsrc, lb);
        }
        __syncthreads();
        bf16x8 af[4], bfr[4];
#pragma unroll
        for (int m = 0; m < 4; m++) {
            af[m]  = *(const bf16x8*)(const void*)&As[(wr + m * 16 + lrow) * 32 + ck];
            bfr[m] = *(const bf16x8*)(const void*)&Bs[(wc + m * 16 + lrow) * 32 + ck];
        }
#pragma unroll
        for (int m = 0; m < 4; m++)
#pragma unroll
            for (int n = 0; n < 4; n++)
                acc[m][n] = __builtin_amdgcn_mfma_f32_16x16x32_bf16(af[m], bfr[n], acc[m][n], 0, 0, 0);
        __syncthreads();
    }

    float* Cf = (float*)Cv;
    __hip_bfloat16* Cb = (__hip_bfloat16*)Cv;
#pragma unroll
    for (int m = 0; m < 4; m++) {
        const int gr = bm + wr + m * 16 + lk * 4;
#pragma unroll
        for (int n = 0; n < 4; n++) {
            const int gc = bn + wc + n * 16 + lrow;
            if (gc >= N) continue;
            const float bv = bias ? bias[gc] : 0.f;
#pragma unroll
            for (int j = 0; j < 4; j++) {
                float v = acc[m][n][j] + bv;
                const int grow = gr + j;
                if (flags & FLAG_GELU) {
                    float x = v;
                    float t = tanhf(0.7978845608028654f * (x + 0.044715f * x * x * x));
                    v = 0.5f * x * (1.0f + t);
                }
                if (flags & FLAG_PERM) {
                    const int mg = moff + grow;
                    const int b_ = mg >> 13, t_ = (mg >> 7) & 63, n_ = mg & 127;
                    Cf[(((long)(b_ * 128 + n_)) * 64 + t_) * ldc + gc] = v;
                } else if (flags & FLAG_BF16) {
                    Cb[(long)grow * ldc + gc] = __float2bfloat16(v);
                } else if (flags & FLAG_ACC) {
                    Cf[(long)grow * ldc + gc] += v;
                } else {
                    Cf[(long)grow * ldc + gc] = v;
                }
            }
        }
    }
}

// ---------------- weight transpose-convert: W (KxN f32) -> WT (Npad x K bf16) ----
__global__ void convT_kernel(const float* __restrict__ W, __hip_bfloat16* __restrict__ WT,
                             int K, int N, int Npad)
{
    __shared__ float t[32][33];
    const int k0 = blockIdx.y * 32, n0 = blockIdx.x * 32;
    const int tx = threadIdx.x & 31, ty = threadIdx.x >> 5;   // 32x8
#pragma unroll
    for (int i = 0; i < 4; i++) {
        int k = k0 + ty + i * 8, n = n0 + tx;
        t[ty + i * 8][tx] = (k < K && n < N) ? W[(long)k * N + n] : 0.f;
    }
    __syncthreads();
#pragma unroll
    for (int i = 0; i < 4; i++) {
        int n = n0 + ty + i * 8, k = k0 + tx;
        if (n < Npad && k < K) WT[(long)n * K + k] = __float2bfloat16(t[tx][ty + i * 8]);
    }
}

// ---------------- f32 -> bf16 elementwise (count in float4s) ----------------
__global__ void cvt_kernel(const float4* __restrict__ x, ushort4* __restrict__ y, long n4)
{
    long i = (long)blockIdx.x * 256 + threadIdx.x;
    if (i >= n4) return;
    float4 v = x[i];
    __hip_bfloat16 a = __float2bfloat16(v.x), b = __float2bfloat16(v.y);
    __hip_bfloat16 c = __float2bfloat16(v.z), d = __float2bfloat16(v.w);
    ushort4 o = { *(ushort*)&a, *(ushort*)&b, *(ushort*)&c, *(ushort*)&d };
    y[i] = o;
}

// ---------------- RMSNorm: f32 in -> bf16 out (strided variants) ----------------
__global__ void rmsnorm_kernel(const float* __restrict__ x, const float* __restrict__ w,
                               __hip_bfloat16* __restrict__ out, int D, int xstride, int ostride)
{
    const long row = blockIdx.x;
    const float* xr = x + row * (long)xstride;
    __hip_bfloat16* orow = out + row * (long)ostride;
    float ss = 0.f;
    for (int i = threadIdx.x; i < D; i += 256) { float v = xr[i]; ss += v * v; }
    __shared__ float red[256];
    red[threadIdx.x] = ss;
    __syncthreads();
    for (int s = 128; s > 0; s >>= 1) {
        if (threadIdx.x < s) red[threadIdx.x] += red[threadIdx.x + s];
        __syncthreads();
    }
    float scale = rsqrtf(red[0] / D + 1e-5f);
    for (int i = threadIdx.x; i < D; i += 256)
        orow[i] = __float2bfloat16(xr[i] * scale * w[i]);
}

// ---------------- fused attention (bf16 in/out, f32 compute) ----------------
__global__ __launch_bounds__(256) void attn_kernel(
    const __hip_bfloat16* __restrict__ Q, const __hip_bfloat16* __restrict__ K,
    const __hip_bfloat16* __restrict__ V, __hip_bfloat16* __restrict__ O)
{
    __shared__ float Qs[64 * 96];   // later reused for V
    __shared__ float Ks[64 * 96];   // first 4096 reused for P
    const int b = blockIdx.x >> 3, h = blockIdx.x & 7;
    const int tid = threadIdx.x;
    const long base = (long)b * 64 * 768 + h * 96;
    for (int i = tid; i < 6144; i += 256) {
        int t = i / 96, d = i - t * 96;
        Qs[i] = __bfloat162float(Q[base + (long)t * 768 + d]);
        Ks[i] = __bfloat162float(K[base + (long)t * 768 + d]);
    }
    __syncthreads();
    const int i_ = tid >> 2, j0 = (tid & 3) << 4;
    float sv[16];
    const float scale = 0.102062072615966f;   // 1/sqrt(96)
#pragma unroll
    for (int jj = 0; jj < 16; jj++) {
        float s = 0.f;
        const float* qr = &Qs[i_ * 96];
        const float* kr = &Ks[(j0 + jj) * 96];
        for (int d = 0; d < 96; d++) s += qr[d] * kr[d];
        sv[jj] = s * scale;
    }
    float mx = sv[0];
#pragma unroll
    for (int jj = 1; jj < 16; jj++) mx = fmaxf(mx, sv[jj]);
    mx = fmaxf(mx, __shfl_xor(mx, 1));
    mx = fmaxf(mx, __shfl_xor(mx, 2));
    float sum = 0.f;
#pragma unroll
    for (int jj = 0; jj < 16; jj++) { sv[jj] = expf(sv[jj] - mx); sum += sv[jj]; }
    sum += __shfl_xor(sum, 1);
    sum += __shfl_xor(sum, 2);
    float inv = 1.f / sum;
    __syncthreads();
    float* Ps = Ks;
#pragma unroll
    for (int jj = 0; jj < 16; jj++) Ps[i_ * 64 + j0 + jj] = sv[jj] * inv;
    for (int i = tid; i < 6144; i += 256) {
        int t = i / 96, d = i - t * 96;
        Qs[i] = __bfloat162float(V[base + (long)t * 768 + d]);
    }
    __syncthreads();
    for (int i = tid; i < 6144; i += 256) {
        int t = i / 96, d = i - t * 96;
        float o = 0.f;
        for (int k = 0; k < 64; k++) o += Ps[t * 64 + k] * Qs[k * 96 + d];
        O[base + (long)t * 768 + d] = __float2bfloat16(o);
    }
}

// ---------------- transpose p (B,N,T,D) -> z (B,T,N,D) ----------------
__global__ void transpose_kernel(const float* __restrict__ P, float* __restrict__ Z)
{
    long lin = (long)blockIdx.x * 256 + threadIdx.x;
    if (lin >= HALF) return;
    int d = (int)(lin % 768);
    long rowz = lin / 768;
    int n = rowz & 127, t = (int)((rowz >> 7) & 63), b = (int)(rowz >> 13);
    long rowp = ((long)(b * 128 + n)) * 64 + t;
    Z[lin] = P[rowp * 768 + d];
}

// ---------------- causal depthwise conv (window 4) + SiLU ----------------
__global__ void conv_kernel(const float* __restrict__ zx, const float* __restrict__ cw,
                            const float* __restrict__ cb, float* __restrict__ xc, int rows)
{
    long lin = (long)blockIdx.x * 256 + threadIdx.x;
    if (lin >= (long)rows * LD_XC) return;
    int c = (int)(lin % LD_XC);
    int r = (int)(lin / LD_XC);
    int n = r & 127;
    float acc = cb[c];
#pragma unroll
    for (int k = 0; k < 4; k++) {
        int nn = n - 3 + k;
        if (nn >= 0) acc += cw[k * LD_XC + c] * zx[(long)(r - 3 + k) * LD_ZX + 1536 + c];
    }
    acc = acc / (1.f + expf(-acc));   // silu
    xc[(long)r * LD_XC + c] = acc;
}

// ---------------- dt = softplus(dt_raw + bias), in place ----------------
__global__ void dt_kernel(float* __restrict__ zx, const float* __restrict__ bias, long count)
{
    long lin = (long)blockIdx.x * 256 + threadIdx.x;
    if (lin >= count) return;
    int h = (int)(lin % 24);
    long r = lin / 24;
    float v = zx[r * LD_ZX + 3200 + h] + bias[h];
    float sp = (v > 0.f) ? v + log1pf(expf(-v)) : log1pf(expf(v));
    zx[r * LD_ZX + 3200 + h] = sp;
}

// ---------------- SSM scan: 1 wave per (bt, head), state in registers ----------------
__global__ __launch_bounds__(64) void scan_kernel(
    const float* __restrict__ zx, float* __restrict__ xc,
    const float* __restrict__ Alog, const float* __restrict__ Dskip,
    float* __restrict__ hout, int bt0)
{
    const int btl = blockIdx.x / 24, h = blockIdx.x % 24;
    const int lane = threadIdx.x;
    const float A = -expf(Alog[h]);
    const float Dh = Dskip[h];
    float hs[64];
#pragma unroll
    for (int s = 0; s < 64; s++) hs[s] = 0.f;
    __shared__ float Bsh[64], Csh[64];
    const long rbase = (long)btl * 128;
    for (int t = 0; t < 128; t++) {
        const long r = rbase + t;
        float x = xc[r * LD_XC + h * 64 + lane];
        Bsh[lane] = xc[r * LD_XC + 1536 + lane];
        Csh[lane] = xc[r * LD_XC + 1600 + lane];
        float dt = zx[r * LD_ZX + 3200 + h];
        __syncthreads();
        float dA = expf(dt * A);
        float coef = dt * x;
        float acc = 0.f;
#pragma unroll
        for (int s = 0; s < 64; s++) {
            hs[s] = hs[s] * dA + coef * Bsh[s];
            acc += hs[s] * Csh[s];
        }
        float zg = zx[r * LD_ZX + h * 64 + lane];
        float y = (acc + Dh * x) * (zg / (1.f + expf(-zg)));
        xc[r * LD_XC + h * 64 + lane] = y;
        __syncthreads();
    }
    if (hout) {
        long base = ((long)(bt0 + btl) * 24 + h) * 4096 + (long)lane * 64;
#pragma unroll
        for (int s = 0; s < 64; s++) hout[base + s] = hs[s];
    }
}

// ---------------- host orchestration ----------------
extern "C" void kernel_launch(void* const* d_in, const int* in_sizes, int n_in,
                              void* d_out, int out_size, void* d_ws, size_t ws_size,
                              hipStream_t stream)
{
    const float* precepts  = (const float*)d_in[0];
    const float* actions   = (const float*)d_in[1];
    const float* attn_n1   = (const float*)d_in[2];
    const float* Wq        = (const float*)d_in[3];
    const float* Wk        = (const float*)d_in[4];
    const float* Wv        = (const float*)d_in[5];
    const float* Wo        = (const float*)d_in[6];
    const float* attn_n2   = (const float*)d_in[7];
    const float* ffn_w1    = (const float*)d_in[8];
    const float* ffn_b1    = (const float*)d_in[9];
    const float* ffn_w2    = (const float*)d_in[10];
    const float* ffn_b2    = (const float*)d_in[11];
    const float* ssm_norm  = (const float*)d_in[12];
    const float* in_proj   = (const float*)d_in[13];
    const float* conv_w    = (const float*)d_in[14];
    const float* conv_b    = (const float*)d_in[15];
    const float* dt_bias   = (const float*)d_in[16];
    const float* A_log     = (const float*)d_in[17];
    const float* D_skip    = (const float*)d_in[18];
    const float* mamba_nw  = (const float*)d_in[19];
    const float* out_proj  = (const float*)d_in[20];
    const float* proj_w    = (const float*)d_in[21];
    const float* proj_b    = (const float*)d_in[22];

    float* out  = (float*)d_out;
    float* Z    = out;            // z residual lives in out[0:HALF] (dead before final GEMM)
    float* P    = out + HALF;     // attention residual (dead before h_last written)
    float* hout = out + HALF;

    // ---- ws layout: bf16 transposed weights, then phase-union scratch ----
    __hip_bfloat16* wb = (__hip_bfloat16*)d_ws;
    long wo = 0;
    auto walloc = [&](long els) { __hip_bfloat16* p = wb + wo; wo += els; return p; };
    __hip_bfloat16* WqT   = walloc(4L * 768 * 768);
    __hip_bfloat16* WkT   = walloc(4L * 768 * 768);
    __hip_bfloat16* WvT   = walloc(4L * 768 * 768);
    __hip_bfloat16* WoT   = walloc(4L * 768 * 768);
    __hip_bfloat16* W1T   = walloc(4L * 3072 * 768);
    __hip_bfloat16* W2T   = walloc(4L * 768 * 3072);
    __hip_bfloat16* inT   = walloc(4L * 3328 * 768);
    __hip_bfloat16* outT  = walloc(4L * 768 * 1536);
    __hip_bfloat16* projT = walloc(768L * 768);
    char* pbase = (char*)(wb + ((wo + 127) & ~127L));
    const size_t used_w = (size_t)((char*)pbase - (char*)d_ws);
    const size_t avail = ws_size > used_w ? ws_size - used_w : 0;

    int CBT = 64;
    while (CBT > 2 && (unsigned long long)CBT * 3092480ull > avail) CBT >>= 1;
    int CB = 128;
    while (CB > 16 && (unsigned long long)CB * 884736ull > avail) CB >>= 1;

    auto gemm = [&](const __hip_bfloat16* A, const __hip_bfloat16* BT, const float* bias,
                    void* C, int ldc, int M, int N, int Npad, int K, int flags, int moff) {
        dim3 g(Npad / 128, M / 128);
        hipLaunchKernelGGL(gemm_bf16, g, dim3(256), 0, stream,
                           A, BT, bias, C, ldc, M, N, K, flags, moff);
    };
    auto cvtT = [&](const float* W, __hip_bfloat16* WT, int K, int N, int Npad) {
        dim3 g((Npad + 31) / 32, (K + 31) / 32);
        hipLaunchKernelGGL(convT_kernel, g, dim3(256), 0, stream, W, WT, K, N, Npad);
    };
    auto cvt = [&](const float* x, __hip_bfloat16* y, long n) {  // n elements (div by 4)
        long n4 = n / 4;
        hipLaunchKernelGGL(cvt_kernel, dim3((n4 + 255) / 256), dim3(256), 0, stream,
                           (const float4*)x, (ushort4*)y, n4);
    };

    // ---- weight conversion (every call; deterministic) ----
    for (int l = 0; l < 4; l++) {
        cvtT(Wq + (long)l * 589824, WqT + (long)l * 589824, 768, 768, 768);
        cvtT(Wk + (long)l * 589824, WkT + (long)l * 589824, 768, 768, 768);
        cvtT(Wv + (long)l * 589824, WvT + (long)l * 589824, 768, 768, 768);
        cvtT(Wo + (long)l * 589824, WoT + (long)l * 589824, 768, 768, 768);
        cvtT(ffn_w1 + (long)l * 2359296, W1T + (long)l * 2359296, 768, 3072, 3072);
        cvtT(ffn_w2 + (long)l * 2359296, W2T + (long)l * 2359296, 3072, 768, 768);
    }
    for (int m = 0; m < 4; m++) {
        cvtT(in_proj + (long)m * 768 * 3224, inT + (long)m * 3328 * 768, 768, 3224, 3328);
        cvtT(out_proj + (long)m * 1536 * 768, outT + (long)m * 768 * 1536, 1536, 768, 768);
    }
    cvtT(proj_w, projT, 768, 768, 768);

    // ---- attention stack ----
    hipMemcpyAsync(P, precepts, HALF * sizeof(float), hipMemcpyDeviceToDevice, stream);
    {
        const long ab = (long)CB * 98304;   // bytes of one 768-wide bf16 chunk buffer
        __hip_bfloat16* actB = (__hip_bfloat16*)pbase;
        __hip_bfloat16* bufA = (__hip_bfloat16*)(pbase + ab);
        __hip_bfloat16* bufQ = (__hip_bfloat16*)(pbase + 2 * ab);
        __hip_bfloat16* bufK = (__hip_bfloat16*)(pbase + 3 * ab);
        __hip_bfloat16* bufV = (__hip_bfloat16*)(pbase + 4 * ab);
        __hip_bfloat16* bufH = (__hip_bfloat16*)(pbase + 5 * ab);
        const int nac = 512 / CB;
        for (int layer = 0; layer < 4; layer++) {
            const bool cross = ((layer + 1) % 2) == 0;
            for (int c = 0; c < nac; c++) {
                const long tok0 = (long)c * CB * 64;
                const int Mr = CB * 64;
                float* Pc = P + tok0 * 768;
                hipLaunchKernelGGL(rmsnorm_kernel, dim3(Mr), dim3(256), 0, stream,
                                   Pc, attn_n1 + layer * 768, bufA, 768, 768, 768);
                gemm(bufA, WqT + (long)layer * 589824, nullptr, bufQ, 768,
                     Mr, 768, 768, 768, FLAG_BF16, 0);
                const __hip_bfloat16* kvsrc = bufA;
                if (cross) {
                    cvt(actions + tok0 * 768, actB, (long)Mr * 768);
                    kvsrc = actB;
                }
                gemm(kvsrc, WkT + (long)layer * 589824, nullptr, bufK, 768,
                     Mr, 768, 768, 768, FLAG_BF16, 0);
                gemm(kvsrc, WvT + (long)layer * 589824, nullptr, bufV, 768,
                     Mr, 768, 768, 768, FLAG_BF16, 0);
                hipLaunchKernelGGL(attn_kernel, dim3(CB * 8), dim3(256), 0, stream,
                                   bufQ, bufK, bufV, bufA);
                gemm(bufA, WoT + (long)layer * 589824, nullptr, Pc, 768,
                     Mr, 768, 768, 768, FLAG_ACC, 0);
                hipLaunchKernelGGL(rmsnorm_kernel, dim3(Mr), dim3(256), 0, stream,
                                   Pc, attn_n2 + layer * 768, bufA, 768, 768, 768);
                gemm(bufA, W1T + (long)layer * 2359296, ffn_b1 + layer * 3072, bufH, 3072,
                     Mr, 3072, 3072, 768, FLAG_GELU | FLAG_BF16, 0);
                gemm(bufH, W2T + (long)layer * 2359296, ffn_b2 + layer * 768, Pc, 768,
                     Mr, 768, 768, 3072, FLAG_ACC, 0);
            }
        }
    }

    // ---- transpose to SSM layout: Z in out[0:HALF] ----
    hipLaunchKernelGGL(transpose_kernel, dim3((HALF + 255) / 256), dim3(256), 0, stream, P, Z);

    // ---- mamba blocks ----
    {
        __hip_bfloat16* xn = (__hip_bfloat16*)pbase;
        float* zx = (float*)(pbase + (long)CBT * 196608);
        float* xc = (float*)((char*)zx + (long)CBT * 1650688);
        __hip_bfloat16* yb = (__hip_bfloat16*)((char*)xc + (long)CBT * 851968);
        const int nmc = 256 / CBT;
        for (int m = 0; m < 4; m++) {
            for (int c = 0; c < nmc; c++) {
                const long row0 = (long)c * CBT * 128;
                const int Mr = CBT * 128;
                float* Zc = Z + row0 * 768;
                hipLaunchKernelGGL(rmsnorm_kernel, dim3(Mr), dim3(256), 0, stream,
                                   Zc, ssm_norm + m * 768, xn, 768, 768, 768);
                gemm(xn, inT + (long)m * 3328 * 768, nullptr, zx, LD_ZX,
                     Mr, 3224, 3328, 768, 0, 0);
                const long convn = (long)Mr * LD_XC;
                hipLaunchKernelGGL(conv_kernel, dim3((convn + 255) / 256), dim3(256), 0, stream,
                                   zx, conv_w + m * 4 * 1664, conv_b + m * 1664, xc, Mr);
                const long dtn = (long)Mr * 24;
                hipLaunchKernelGGL(dt_kernel, dim3((dtn + 255) / 256), dim3(256), 0, stream,
                                   zx, dt_bias + m * 24, dtn);
                hipLaunchKernelGGL(scan_kernel, dim3(CBT * 24), dim3(64), 0, stream,
                                   zx, xc, A_log + m * 24, D_skip + m * 24,
                                   (m == 3) ? hout : nullptr, c * CBT);
                hipLaunchKernelGGL(rmsnorm_kernel, dim3(Mr), dim3(256), 0, stream,
                                   xc, mamba_nw + m * 1536, yb, 1536, 1664, 1536);
                gemm(yb, outT + (long)m * 768 * 1536, nullptr, Zc, 768,
                     Mr, 768, 768, 1536, FLAG_ACC, 0);
            }
        }
    }

    // ---- final projection (chunked; convert Z chunk, GEMM with permuted epilogue) ----
    {
        __hip_bfloat16* Zb = (__hip_bfloat16*)pbase;
        for (int c = 0; c < 4; c++) {
            const long row0 = (long)c * 8192;
            cvt(Z + row0 * 768, Zb, 8192L * 768);
            gemm(Zb, projT, proj_b, out, 768, 8192, 768, 768, 768, FLAG_PERM, (int)row0);
        }
    }
}

// Round 3
// 10267.765 us; speedup vs baseline: 6.8634x; 1.5092x over previous
//
#include <hip/hip_runtime.h>
#include <hip/hip_bf16.h>
#include <math.h>

// ---------------- model dims ----------------
constexpr long TOK  = 32768;            // B*N*T
constexpr long HALF = TOK * 768;
constexpr int FLAG_ACC = 1, FLAG_GELU = 2, FLAG_PERM = 4, FLAG_BF16 = 8;

typedef __bf16 bf16x8 __attribute__((ext_vector_type(8)));
typedef float  f32x4  __attribute__((ext_vector_type(4)));

__device__ __forceinline__ void gload_lds16(const void* g, void* l) {
    __builtin_amdgcn_global_load_lds(
        (const __attribute__((address_space(1))) void*)g,
        (__attribute__((address_space(3))) void*)l, 16, 0, 0);
}
__device__ __forceinline__ float bf2f(__hip_bfloat16 v) { return __bfloat162float(v); }

// ---------------- bf16 MFMA GEMM (128x128 tile, XCD-swizzled) ----------------
__global__ __launch_bounds__(256) void gemm_bf16(
    const __hip_bfloat16* __restrict__ A,
    const __hip_bfloat16* __restrict__ BT,
    const float* __restrict__ bias,
    void* __restrict__ Cv, int ldc,
    int M, int N, int K, int flags, int moff)
{
    __shared__ __hip_bfloat16 As[128 * 32];
    __shared__ __hip_bfloat16 Bs[128 * 32];
    const int tid = threadIdx.x;
    const int wv = tid >> 6, lane = tid & 63;
    // bijective XCD swizzle (m204)
    const int nwg = gridDim.x * gridDim.y;
    const int orig = blockIdx.y * gridDim.x + blockIdx.x;
    const int q8 = nwg >> 3, r8 = nwg & 7;
    const int xcd = orig & 7, off = orig >> 3;
    const int wgid = (xcd < r8 ? xcd * (q8 + 1) : r8 * (q8 + 1) + (xcd - r8) * q8) + off;
    const int bm = (wgid / gridDim.x) * 128, bn = (wgid % gridDim.x) * 128;
    const int wr = (wv >> 1) * 64, wc = (wv & 1) * 64;
    const int lrow = lane & 15, lk = lane >> 4;
    const int ck = (lk ^ (lrow & 3)) * 8;

    f32x4 acc[4][4];
#pragma unroll
    for (int m = 0; m < 4; m++)
#pragma unroll
        for (int n = 0; n < 4; n++) acc[m][n] = f32x4{0.f, 0.f, 0.f, 0.f};

    for (int k0 = 0; k0 < K; k0 += 32) {
#pragma unroll
        for (int i = 0; i < 2; i++) {
            const int lin = i * 256 + tid;
            const int row = lin >> 2;
            const int ks  = (((lin & 3) ^ (row & 3)) * 8);
            const long asrc = (long)(bm + row) * K + k0 + ks;
            const long bsrc = (long)(bn + row) * K + k0 + ks;
            char* la = (char*)As + (i * 256 + wv * 64) * 16;
            char* lb = (char*)Bs + (i * 256 + wv * 64) * 16;
            gload_lds16(A + asrc, la);
            gload_lds16(BT + bsrc, lb);
        }
        __syncthreads();
        bf16x8 af[4], bfr[4];
#pragma unroll
        for (int m = 0; m < 4; m++) {
            af[m]  = *(const bf16x8*)(const void*)&As[(wr + m * 16 + lrow) * 32 + ck];
            bfr[m] = *(const bf16x8*)(const void*)&Bs[(wc + m * 16 + lrow) * 32 + ck];
        }
#pragma unroll
        for (int m = 0; m < 4; m++)
#pragma unroll
            for (int n = 0; n < 4; n++)
                acc[m][n] = __builtin_amdgcn_mfma_f32_16x16x32_bf16(af[m], bfr[n], acc[m][n], 0, 0, 0);
        __syncthreads();
    }

    float* Cf = (float*)Cv;
    __hip_bfloat16* Cb = (__hip_bfloat16*)Cv;
#pragma unroll
    for (int m = 0; m < 4; m++) {
        const int gr = bm + wr + m * 16 + lk * 4;
#pragma unroll
        for (int n = 0; n < 4; n++) {
            const int gc = bn + wc + n * 16 + lrow;
            if (gc >= N) continue;
            const float bv = bias ? bias[gc] : 0.f;
#pragma unroll
            for (int j = 0; j < 4; j++) {
                float v = acc[m][n][j] + bv;
                const int grow = gr + j;
                if (flags & FLAG_GELU) {
                    float x = v;
                    float t = tanhf(0.7978845608028654f * (x + 0.044715f * x * x * x));
                    v = 0.5f * x * (1.0f + t);
                }
                if (flags & FLAG_PERM) {
                    const int mg = moff + grow;
                    const int b_ = mg >> 13, t_ = (mg >> 7) & 63, n_ = mg & 127;
                    Cf[(((long)(b_ * 128 + n_)) * 64 + t_) * ldc + gc] = v;
                } else if (flags & FLAG_BF16) {
                    Cb[(long)grow * ldc + gc] = __float2bfloat16(v);
                } else if (flags & FLAG_ACC) {
                    Cf[(long)grow * ldc + gc] += v;
                } else {
                    Cf[(long)grow * ldc + gc] = v;
                }
            }
        }
    }
}

// ---------------- weight transpose-convert: W (KxN f32) -> WT (Npad x K bf16) ----
__global__ void convT_kernel(const float* __restrict__ W, __hip_bfloat16* __restrict__ WT,
                             int K, int N, int Npad)
{
    __shared__ float t[32][33];
    const int k0 = blockIdx.y * 32, n0 = blockIdx.x * 32;
    const int tx = threadIdx.x & 31, ty = threadIdx.x >> 5;
#pragma unroll
    for (int i = 0; i < 4; i++) {
        int k = k0 + ty + i * 8, n = n0 + tx;
        t[ty + i * 8][tx] = (k < K && n < N) ? W[(long)k * N + n] : 0.f;
    }
    __syncthreads();
#pragma unroll
    for (int i = 0; i < 4; i++) {
        int n = n0 + ty + i * 8, k = k0 + tx;
        if (n < Npad && k < K) WT[(long)n * K + k] = __float2bfloat16(t[tx][ty + i * 8]);
    }
}

// ---------------- f32 -> bf16 elementwise ----------------
__global__ void cvt_kernel(const float4* __restrict__ x, ushort4* __restrict__ y, long n4)
{
    long i = (long)blockIdx.x * 256 + threadIdx.x;
    if (i >= n4) return;
    float4 v = x[i];
    __hip_bfloat16 a = __float2bfloat16(v.x), b = __float2bfloat16(v.y);
    __hip_bfloat16 c = __float2bfloat16(v.z), d = __float2bfloat16(v.w);
    ushort4 o = { *(ushort*)&a, *(ushort*)&b, *(ushort*)&c, *(ushort*)&d };
    y[i] = o;
}

// ---------------- RMSNorm, wave-per-row (f32 / bf16 input) ----------------
__global__ void rmsnorm_f32(const float* __restrict__ x, const float* __restrict__ w,
                            __hip_bfloat16* __restrict__ out, int D, int xs, int os, long nrows)
{
    const int wv = threadIdx.x >> 6, lane = threadIdx.x & 63;
    const long row = (long)blockIdx.x * 4 + wv;
    if (row >= nrows) return;
    const float* xr = x + row * xs;
    float ss = 0.f;
    for (int i = lane; i < D; i += 64) { float v = xr[i]; ss += v * v; }
    for (int o = 32; o; o >>= 1) ss += __shfl_xor(ss, o);
    const float sc = rsqrtf(ss / D + 1e-5f);
    __hip_bfloat16* orow = out + row * os;
    for (int i = lane; i < D; i += 64) orow[i] = __float2bfloat16(xr[i] * sc * w[i]);
}
__global__ void rmsnorm_b16(const __hip_bfloat16* __restrict__ x, const float* __restrict__ w,
                            __hip_bfloat16* __restrict__ out, int D, int xs, int os, long nrows)
{
    const int wv = threadIdx.x >> 6, lane = threadIdx.x & 63;
    const long row = (long)blockIdx.x * 4 + wv;
    if (row >= nrows) return;
    const __hip_bfloat16* xr = x + row * xs;
    float ss = 0.f;
    for (int i = lane; i < D; i += 64) { float v = bf2f(xr[i]); ss += v * v; }
    for (int o = 32; o; o >>= 1) ss += __shfl_xor(ss, o);
    const float sc = rsqrtf(ss / D + 1e-5f);
    __hip_bfloat16* orow = out + row * os;
    for (int i = lane; i < D; i += 64) orow[i] = __float2bfloat16(bf2f(xr[i]) * sc * w[i]);
}

// ---------------- fused attention: per (batch, head), float4 LDS ----------------
// QKV: [64 x 2304] bf16 per batch (Q|K|V). O: [64 x 768] bf16.
__global__ __launch_bounds__(256) void attn_kernel(
    const __hip_bfloat16* __restrict__ QKV, __hip_bfloat16* __restrict__ O)
{
    __shared__ float Qs[64 * 100];   // later overlaid by Ps (64x65)
    __shared__ float Ks[64 * 100];   // later overlaid by Vs (64x100)
    const int b = blockIdx.x >> 3, h = blockIdx.x & 7;
    const int tid = threadIdx.x;
    const long base = (long)b * 64 * 2304 + h * 96;
    for (int i = tid; i < 6144; i += 256) {
        int t = i / 96, d = i - t * 96;
        Qs[t * 100 + d] = bf2f(QKV[base + (long)t * 2304 + d]);
        // Ks with granule-XOR swizzle keyed on (t>>4)&3 to deconflict score reads
        int g = ((d >> 2) ^ ((t >> 4) & 3)) << 2;
        Ks[t * 100 + g + (d & 3)] = bf2f(QKV[base + (long)t * 2304 + 768 + d]);
    }
    __syncthreads();
    const int i_ = tid >> 2, j0 = (tid & 3) << 4;
    float sv[16];
#pragma unroll
    for (int jj = 0; jj < 16; jj++) sv[jj] = 0.f;
    for (int d0 = 0; d0 < 96; d0 += 4) {
        const float4 q4 = *(const float4*)&Qs[i_ * 100 + d0];
#pragma unroll
        for (int jj = 0; jj < 16; jj++) {
            const int r = j0 + jj;
            const int g = (((d0 >> 2) ^ ((r >> 4) & 3)) << 2);
            const float4 k4 = *(const float4*)&Ks[r * 100 + g];
            sv[jj] += q4.x * k4.x + q4.y * k4.y + q4.z * k4.z + q4.w * k4.w;
        }
    }
    const float scale = 0.102062072615966f;   // 1/sqrt(96)
    float mx = sv[0] * scale;
#pragma unroll
    for (int jj = 0; jj < 16; jj++) { sv[jj] *= scale; mx = fmaxf(mx, sv[jj]); }
    mx = fmaxf(mx, __shfl_xor(mx, 1));
    mx = fmaxf(mx, __shfl_xor(mx, 2));
    float sum = 0.f;
#pragma unroll
    for (int jj = 0; jj < 16; jj++) { sv[jj] = expf(sv[jj] - mx); sum += sv[jj]; }
    sum += __shfl_xor(sum, 1);
    sum += __shfl_xor(sum, 2);
    const float inv = 1.f / sum;
    __syncthreads();                 // all reads of Qs/Ks done
    float* Ps = Qs;                  // 64 x 65 (stride 65: bank-free column reads)
#pragma unroll
    for (int jj = 0; jj < 16; jj++) Ps[i_ * 65 + j0 + jj] = sv[jj] * inv;
    float* Vs = Ks;                  // plain 64 x 100
    for (int i = tid; i < 6144; i += 256) {
        int t = i / 96, d = i - t * 96;
        Vs[t * 100 + d] = bf2f(QKV[base + (long)t * 2304 + 1536 + d]);
    }
    __syncthreads();
    const int t_ = tid & 63, dg = (tid >> 6) * 24;
    float o4[24];
#pragma unroll
    for (int c = 0; c < 24; c++) o4[c] = 0.f;
    for (int k = 0; k < 64; k++) {
        const float p = Ps[t_ * 65 + k];           // stride-65: conflict-free
#pragma unroll
        for (int c = 0; c < 6; c++) {
            const float4 v4 = *(const float4*)&Vs[k * 100 + dg + c * 4];  // broadcast
            o4[c * 4 + 0] += p * v4.x; o4[c * 4 + 1] += p * v4.y;
            o4[c * 4 + 2] += p * v4.z; o4[c * 4 + 3] += p * v4.w;
        }
    }
    const long ob = (long)(b * 64 + t_) * 768 + h * 96 + dg;
#pragma unroll
    for (int c = 0; c < 24; c++) O[ob + c] = __float2bfloat16(o4[c]);
}

// ---------------- transpose p (B,N,T,D) -> z (B,T,N,D) ----------------
__global__ void transpose_kernel(const float* __restrict__ P, float* __restrict__ Z)
{
    long lin = (long)blockIdx.x * 256 + threadIdx.x;
    if (lin >= HALF) return;
    int d = (int)(lin % 768);
    long rowz = lin / 768;
    int n = rowz & 127, t = (int)((rowz >> 7) & 63), b = (int)(rowz >> 13);
    long rowp = ((long)(b * 128 + n)) * 64 + t;
    Z[lin] = P[rowp * 768 + d];
}

// ---------------- causal depthwise conv (window 4) + SiLU : bf16 in/out --------
__global__ void conv_kernel(const __hip_bfloat16* __restrict__ zx,
                            const float* __restrict__ cw, const float* __restrict__ cb,
                            __hip_bfloat16* __restrict__ xc, long rows)
{
    long lin = (long)blockIdx.x * 256 + threadIdx.x;
    if (lin >= rows * 1664) return;
    int c = (int)(lin % 1664);
    long r = lin / 1664;
    int n = (int)(r & 127);
    float acc = cb[c];
#pragma unroll
    for (int k = 0; k < 4; k++) {
        int nn = n - 3 + k;
        if (nn >= 0) acc += cw[k * 1664 + c] * bf2f(zx[(r - 3 + k) * 3328 + 1536 + c]);
    }
    acc = acc / (1.f + expf(-acc));
    xc[lin] = __float2bfloat16(acc);
}

// ---------------- dt = softplus(dt_raw + bias) -> f32 side buffer ----------------
__global__ void dt_kernel(const __hip_bfloat16* __restrict__ zx, const float* __restrict__ bias,
                          float* __restrict__ dtf, long count)
{
    long lin = (long)blockIdx.x * 256 + threadIdx.x;
    if (lin >= count) return;
    int h = (int)(lin % 24);
    long r = lin / 24;
    float v = bf2f(zx[r * 3328 + 3200 + h]) + bias[h];
    dtf[lin] = (v > 0.f) ? v + log1pf(expf(-v)) : log1pf(expf(v));
}

// ---------------- SSM scan: 1 wave per (bt, head), full extent ----------------
__global__ __launch_bounds__(64) void scan_kernel(
    const __hip_bfloat16* __restrict__ zx, const float* __restrict__ dtf,
    __hip_bfloat16* __restrict__ xc,
    const float* __restrict__ Alog, const float* __restrict__ Dskip,
    float* __restrict__ hout, int bt0)
{
    const int btl = blockIdx.x / 24, h = blockIdx.x % 24;
    const int lane = threadIdx.x;
    const float A = -expf(Alog[h]);
    const float Dh = Dskip[h];
    float hs[64];
#pragma unroll
    for (int s = 0; s < 64; s++) hs[s] = 0.f;
    __shared__ float Bsh[64], Csh[64];
    const long rbase = (long)btl * 128;
    for (int t = 0; t < 128; t++) {
        const long r = rbase + t;
        const float x = bf2f(xc[r * 1664 + h * 64 + lane]);
        Bsh[lane] = bf2f(xc[r * 1664 + 1536 + lane]);
        Csh[lane] = bf2f(xc[r * 1664 + 1600 + lane]);
        const float dt = dtf[r * 24 + h];
        const float zg = bf2f(zx[r * 3328 + h * 64 + lane]);
        __syncthreads();
        const float dA = expf(dt * A);
        const float coef = dt * x;
        float acc = 0.f;
#pragma unroll
        for (int s = 0; s < 64; s++) {
            hs[s] = hs[s] * dA + coef * Bsh[s];
            acc += hs[s] * Csh[s];
        }
        const float y = (acc + Dh * x) * (zg / (1.f + expf(-zg)));
        xc[r * 1664 + h * 64 + lane] = __float2bfloat16(y);
        __syncthreads();
    }
    if (hout) {
        long base = ((long)(bt0 + btl) * 24 + h) * 4096 + (long)lane * 64;
#pragma unroll
        for (int s = 0; s < 64; s++) hout[base + s] = hs[s];
    }
}

// ---------------- host orchestration ----------------
extern "C" void kernel_launch(void* const* d_in, const int* in_sizes, int n_in,
                              void* d_out, int out_size, void* d_ws, size_t ws_size,
                              hipStream_t stream)
{
    const float* precepts  = (const float*)d_in[0];
    const float* actions   = (const float*)d_in[1];
    const float* attn_n1   = (const float*)d_in[2];
    const float* Wq        = (const float*)d_in[3];
    const float* Wk        = (const float*)d_in[4];
    const float* Wv        = (const float*)d_in[5];
    const float* Wo        = (const float*)d_in[6];
    const float* attn_n2   = (const float*)d_in[7];
    const float* ffn_w1    = (const float*)d_in[8];
    const float* ffn_b1    = (const float*)d_in[9];
    const float* ffn_w2    = (const float*)d_in[10];
    const float* ffn_b2    = (const float*)d_in[11];
    const float* ssm_norm  = (const float*)d_in[12];
    const float* in_proj   = (const float*)d_in[13];
    const float* conv_w    = (const float*)d_in[14];
    const float* conv_b    = (const float*)d_in[15];
    const float* dt_bias   = (const float*)d_in[16];
    const float* A_log     = (const float*)d_in[17];
    const float* D_skip    = (const float*)d_in[18];
    const float* mamba_nw  = (const float*)d_in[19];
    const float* out_proj  = (const float*)d_in[20];
    const float* proj_w    = (const float*)d_in[21];
    const float* proj_b    = (const float*)d_in[22];

    float* out  = (float*)d_out;
    float* Z    = out;            // z residual in out[0:HALF], dead before final GEMM
    float* P    = out + HALF;     // attention residual, dead before h_last written
    float* hout = out + HALF;

    // ---- ws: bf16 transposed weights, then phase-union scratch ----
    __hip_bfloat16* wb = (__hip_bfloat16*)d_ws;
    long wo = 0;
    auto walloc = [&](long els) { __hip_bfloat16* p = wb + wo; wo += els; return p; };
    __hip_bfloat16* WqkvT = walloc(4L * 2304 * 768);   // per layer: [Wq^T|Wk^T|Wv^T]
    __hip_bfloat16* W1T   = walloc(4L * 3072 * 768);
    __hip_bfloat16* W2T   = walloc(4L * 768 * 3072);
    __hip_bfloat16* inT   = walloc(4L * 3328 * 768);
    __hip_bfloat16* outT  = walloc(4L * 768 * 1536);
    __hip_bfloat16* projT = walloc(768L * 768);
    char* pbase = (char*)(wb + ((wo + 255) & ~255L));
    const size_t used_w = (size_t)(pbase - (char*)d_ws);
    const size_t avail = ws_size > used_w ? ws_size - used_w : 0;

    int CB = 512;                 // attention chunk (batches of 64 tokens)
    while (CB > 8 && (unsigned long long)CB * 884736ull > avail) CB >>= 1;
    int CBT = 256;                // mamba chunk (sequences of 128)
    while (CBT > 2 && (unsigned long long)CBT * 1880064ull > avail) CBT >>= 1;

    auto gemm = [&](const __hip_bfloat16* A, const __hip_bfloat16* BT, const float* bias,
                    void* C, int ldc, int M, int N, int Npad, int K, int flags, int moff) {
        dim3 g(Npad / 128, M / 128);
        hipLaunchKernelGGL(gemm_bf16, g, dim3(256), 0, stream,
                           A, BT, bias, C, ldc, M, N, K, flags, moff);
    };
    auto cvtT = [&](const float* W, __hip_bfloat16* WT, int K, int N, int Npad) {
        dim3 g((Npad + 31) / 32, (K + 31) / 32);
        hipLaunchKernelGGL(convT_kernel, g, dim3(256), 0, stream, W, WT, K, N, Npad);
    };
    auto cvt = [&](const float* x, __hip_bfloat16* y, long n) {
        long n4 = n / 4;
        hipLaunchKernelGGL(cvt_kernel, dim3((n4 + 255) / 256), dim3(256), 0, stream,
                           (const float4*)x, (ushort4*)y, n4);
    };
    auto rmsF = [&](const float* x, const float* w, __hip_bfloat16* o, int D, int xs, int os, long rows) {
        hipLaunchKernelGGL(rmsnorm_f32, dim3((rows + 3) / 4), dim3(256), 0, stream,
                           x, w, o, D, xs, os, rows);
    };
    auto rmsB = [&](const __hip_bfloat16* x, const float* w, __hip_bfloat16* o, int D, int xs, int os, long rows) {
        hipLaunchKernelGGL(rmsnorm_b16, dim3((rows + 3) / 4), dim3(256), 0, stream,
                           x, w, o, D, xs, os, rows);
    };

    // ---- weight conversion ----
    for (int l = 0; l < 4; l++) {
        cvtT(Wq + (long)l * 589824, WqkvT + (long)l * 2304 * 768,                768, 768, 768);
        cvtT(Wk + (long)l * 589824, WqkvT + (long)l * 2304 * 768 +  768L * 768,  768, 768, 768);
        cvtT(Wv + (long)l * 589824, WqkvT + (long)l * 2304 * 768 + 1536L * 768,  768, 768, 768);
        cvtT(ffn_w1 + (long)l * 2359296, W1T + (long)l * 2359296, 768, 3072, 3072);
        cvtT(ffn_w2 + (long)l * 2359296, W2T + (long)l * 2359296, 3072, 768, 768);
    }
    __hip_bfloat16* WoT = projT + 768L * 768;  // reuse tail? no — allocate properly:
    // (Wo needs its own slab; put it after projT via walloc-style fixed offset)
    // NOTE: walloc'd above ended at projT+768*768; carve WoT there and shift pbase.
    {
        // re-derive pbase including WoT (4 * 768*768)
        long wo2 = wo + 4L * 768 * 768;
        pbase = (char*)(wb + ((wo2 + 255) & ~255L));
    }
    for (int l = 0; l < 4; l++)
        cvtT(Wo + (long)l * 589824, WoT + (long)l * 589824, 768, 768, 768);
    for (int m = 0; m < 4; m++) {
        cvtT(in_proj + (long)m * 768 * 3224, inT + (long)m * 3328 * 768, 768, 3224, 3328);
        cvtT(out_proj + (long)m * 1536 * 768, outT + (long)m * 768 * 1536, 1536, 768, 768);
    }
    cvtT(proj_w, projT, 768, 768, 768);

    // recompute avail/chunks with final pbase
    {
        const size_t uw = (size_t)(pbase - (char*)d_ws);
        const size_t av = ws_size > uw ? ws_size - uw : 0;
        CB = 512;  while (CB > 8 && (unsigned long long)CB * 884736ull > av) CB >>= 1;
        CBT = 256; while (CBT > 2 && (unsigned long long)CBT * 1880064ull > av) CBT >>= 1;
    }

    // ---- attention stack ----
    hipMemcpyAsync(P, precepts, HALF * sizeof(float), hipMemcpyDeviceToDevice, stream);
    {
        const long rA = (long)CB * 64;               // rows per chunk
        __hip_bfloat16* bufA   = (__hip_bfloat16*)pbase;                    // rA x 768
        __hip_bfloat16* actB   = bufA + rA * 768;                           // rA x 768
        __hip_bfloat16* bufQKV = actB + rA * 768;                           // rA x 2304
        __hip_bfloat16* bufH   = bufQKV + rA * 2304;                        // rA x 3072
        const int nac = 512 / CB;
        const int Mr = (int)rA;
        if (nac == 1) cvt(actions, actB, rA * 768);  // hoist: both cross layers share it
        for (int layer = 0; layer < 4; layer++) {
            const bool cross = ((layer + 1) % 2) == 0;
            for (int c = 0; c < nac; c++) {
                const long tok0 = (long)c * rA;
                float* Pc = P + tok0 * 768;
                rmsF(Pc, attn_n1 + layer * 768, bufA, 768, 768, 768, Mr);
                if (!cross) {
                    gemm(bufA, WqkvT + (long)layer * 2304 * 768, nullptr, bufQKV, 2304,
                         Mr, 2304, 2304, 768, FLAG_BF16, 0);
                } else {
                    if (nac != 1) cvt(actions + tok0 * 768, actB, rA * 768);
                    gemm(bufA, WqkvT + (long)layer * 2304 * 768, nullptr, bufQKV, 2304,
                         Mr, 768, 768, 768, FLAG_BF16, 0);
                    gemm(actB, WqkvT + (long)layer * 2304 * 768 + 768L * 768, nullptr,
                         bufQKV + 768, 2304, Mr, 1536, 1536, 768, FLAG_BF16, 0);
                }
                hipLaunchKernelGGL(attn_kernel, dim3(CB * 8), dim3(256), 0, stream,
                                   bufQKV, bufA);
                gemm(bufA, WoT + (long)layer * 589824, nullptr, Pc, 768,
                     Mr, 768, 768, 768, FLAG_ACC, 0);
                rmsF(Pc, attn_n2 + layer * 768, bufA, 768, 768, 768, Mr);
                gemm(bufA, W1T + (long)layer * 2359296, ffn_b1 + layer * 3072, bufH, 3072,
                     Mr, 3072, 3072, 768, FLAG_GELU | FLAG_BF16, 0);
                gemm(bufH, W2T + (long)layer * 2359296, ffn_b2 + layer * 768, Pc, 768,
                     Mr, 768, 768, 3072, FLAG_ACC, 0);
            }
        }
    }

    // ---- transpose to SSM layout ----
    hipLaunchKernelGGL(transpose_kernel, dim3((int)((HALF + 255) / 256)), dim3(256), 0, stream, P, Z);

    // ---- mamba blocks ----
    {
        const long rM = (long)CBT * 128;             // rows per chunk
        __hip_bfloat16* xn  = (__hip_bfloat16*)pbase;            // rM x 768
        __hip_bfloat16* zx  = xn + rM * 768;                     // rM x 3328
        float*          dtf = (float*)(zx + rM * 3328);          // rM x 24
        __hip_bfloat16* xc  = (__hip_bfloat16*)(dtf + rM * 24);  // rM x 1664
        __hip_bfloat16* yb  = xc + rM * 1664;                    // rM x 1536
        const int nmc = 256 / CBT;
        const int Mr = (int)rM;
        for (int m = 0; m < 4; m++) {
            for (int c = 0; c < nmc; c++) {
                float* Zc = Z + (long)c * rM * 768;
                rmsF(Zc, ssm_norm + m * 768, xn, 768, 768, 768, Mr);
                gemm(xn, inT + (long)m * 3328 * 768, nullptr, zx, 3328,
                     Mr, 3224, 3328, 768, FLAG_BF16, 0);
                const long convn = rM * 1664;
                hipLaunchKernelGGL(conv_kernel, dim3((int)((convn + 255) / 256)), dim3(256), 0, stream,
                                   zx, conv_w + m * 4 * 1664, conv_b + m * 1664, xc, rM);
                const long dtn = rM * 24;
                hipLaunchKernelGGL(dt_kernel, dim3((int)((dtn + 255) / 256)), dim3(256), 0, stream,
                                   zx, dt_bias + m * 24, dtf, dtn);
                hipLaunchKernelGGL(scan_kernel, dim3(CBT * 24), dim3(64), 0, stream,
                                   zx, dtf, xc, A_log + m * 24, D_skip + m * 24,
                                   (m == 3) ? hout : nullptr, c * CBT);
                rmsB(xc, mamba_nw + m * 1536, yb, 1536, 1664, 1536, Mr);
                gemm(yb, outT + (long)m * 768 * 1536, nullptr, Zc, 768,
                     Mr, 768, 768, 1536, FLAG_ACC, 0);
            }
        }
    }

    // ---- final projection: convert all of Z, then PERM GEMM ----
    {
        __hip_bfloat16* Zb = (__hip_bfloat16*)pbase;
        cvt(Z, Zb, HALF);
        gemm(Zb, projT, proj_b, out, 768, 32768, 768, 768, 768, FLAG_PERM, 0);
    }
}